// Round 4
// baseline (163.076 us; speedup 1.0000x reference)
//
#include <hip/hip_runtime.h>

// y = x @ W_base^T + b + S * adapter(x);  adapter folds into the weight:
//   W_eff[o*64+e][i*64+d] = W_base[..] + S * U[d,i,o] * V[o,d,e]
// => one bf16 GEMM  C[4096][4096] = Xb @ W_eff^T + bias
// GEMM: 256x256 tile, BK=64, 8 waves, mfma_f32_32x32x16_bf16, 4-phase/tile
// counted-vmcnt schedule, LDS [buf][op][half][128][64] with chunk^=(row&7).

typedef __attribute__((ext_vector_type(4)))  float  float4v;
typedef __attribute__((ext_vector_type(16))) float  float16v;
typedef __attribute__((ext_vector_type(8)))  __bf16 bf16x8;
typedef __attribute__((ext_vector_type(4)))  short  short4v;

#define K_TOT 4096
#define M_TOT 4096
#define N_TOT 4096

__device__ __forceinline__ unsigned short f2bf(float f) {
  unsigned int u = __float_as_uint(f);
  u += 0x7FFFu + ((u >> 16) & 1u);
  return (unsigned short)(u >> 16);
}

// ------------- tiny transposes: Ut[i][o][d]=U[d][i][o], Vt[o][e][d]=V[o][d][e]
__global__ void trans_uv(const float* __restrict__ U, const float* __restrict__ V,
                         float* __restrict__ Ut, float* __restrict__ Vt) {
  int idx = blockIdx.x * 256 + threadIdx.x;
  if (idx < 262144) {
    int d = idx & 63, o = (idx >> 6) & 63, i = idx >> 12;
    Ut[idx] = U[(d * 64 + i) * 64 + o];
  } else {
    int j = idx - 262144;
    int d = j & 63, e = (j >> 6) & 63, o = j >> 12;
    Vt[j] = V[(o * 64 + d) * 64 + e];
  }
}

// ------------- fused prep: W_eff = bf16(W + S*Ut*Vt);  Xb = bf16(X) ---------
__global__ void prep_all(const float* __restrict__ W, const float* __restrict__ Ut,
                         const float* __restrict__ Vt, const float* __restrict__ Sp,
                         const float* __restrict__ X,
                         unsigned short* __restrict__ Weff,
                         unsigned short* __restrict__ Xb) {
  const float s = Sp[0];
  const int wq = (N_TOT * K_TOT) / 4;           // 4M quads for W
  const int total4 = wq + (M_TOT * K_TOT) / 4;  // + 4M quads for X
  for (int idx = blockIdx.x * 256 + threadIdx.x; idx < total4;
       idx += gridDim.x * 256) {
    if (idx < wq) {
      const int base = idx << 2;
      const int of = base >> 12, if0 = base & 4095;
      const int o = of >> 6, e = of & 63, i = if0 >> 6, d0 = if0 & 63;
      const float4v wv = *(const float4v*)(W + (size_t)base);
      const float4v u4 = *(const float4v*)(Ut + (i * 64 + o) * 64 + d0);
      const float4v v4 = *(const float4v*)(Vt + (o * 64 + e) * 64 + d0);
      short4v pk;
#pragma unroll
      for (int j = 0; j < 4; ++j) pk[j] = (short)f2bf(wv[j] + s * u4[j] * v4[j]);
      *(short4v*)(Weff + (size_t)base) = pk;
    } else {
      const int base = (idx - wq) << 2;
      const float4v v = *(const float4v*)(X + (size_t)base);
      short4v pk;
#pragma unroll
      for (int j = 0; j < 4; ++j) pk[j] = (short)f2bf(v[j]);
      *(short4v*)(Xb + (size_t)base) = pk;
    }
  }
}

// ---------------- 256x256 GEMM, 32x32x16 MFMA -------------------------------
#define GL16(g, l)                                                    \
  __builtin_amdgcn_global_load_lds(                                   \
      (__attribute__((address_space(1))) void*)(g),                   \
      (__attribute__((address_space(3))) void*)(l), 16, 0, 0)

#define BARRIER() asm volatile("s_barrier" ::: "memory")
#define VMC4() asm volatile("s_waitcnt vmcnt(4)" ::: "memory")
#define VMC0() asm volatile("s_waitcnt vmcnt(0)" ::: "memory")
#define VMNONE()

__global__ __launch_bounds__(512, 2) void gemm256(
    const unsigned short* __restrict__ A,    // [4096][4096] bf16 (X)
    const unsigned short* __restrict__ Bm,   // [4096][4096] bf16 (W_eff)
    const float* __restrict__ bias,
    float* __restrict__ C) {
  // [buf][op A=0/B=1][row-half][128 rows][64 cols bf16] = 128 KiB
  __shared__ unsigned short lds[2][2][2][8192];

  const int tid = threadIdx.x;
  const int w = tid >> 6;
  const int l = tid & 63;
  const int r5 = l & 31;        // MFMA row/col within 32
  const int e3 = l & 7;         // swizzle XOR key (= row&7)
  const int kh = l >> 5;        // k-half selector
  const int rowOff32 = r5 * 64; // ushort offset of lane's row

  // XCD-aware bijective swizzle (256 blocks, 256 % 8 == 0)
  int b = blockIdx.x;
  b = (b & 7) * 32 + (b >> 3);
  const int brow = (b >> 4) * 256;
  const int bcol = (b & 15) * 256;

  const int wr = w >> 2;        // 0..1 -> 128-row half of A-tile
  const int wc = w & 3;         // 0..3 -> 64-row slice of B-tile
  const int wcH = wc >> 1, wcL = wc & 1;

  // per-lane swizzled chunk offsets for k-quarter q (ushorts)
  int ck[4];
#pragma unroll
  for (int q = 0; q < 4; ++q) ck[q] = (((q * 2 + kh) ^ e3) << 3);

  // stage-side inverse: lane covers phys chunk (w*64 + l); row = w*8 + l>>3
  const int rowL = l >> 3;
  const int cL = (l & 7) ^ rowL;
  const unsigned short* pa = A + (size_t)(brow + w * 8 + rowL) * K_TOT + cL * 8;
  const unsigned short* pb = Bm + (size_t)(bcol + w * 8 + rowL) * K_TOT + cL * 8;
  const int ldsC0 = (w * 64) * 8;        // wave chunk base, rows 0-63 of half
  const int ldsC1 = (512 + w * 64) * 8;  // rows 64-127

#define STAGE(gp, BUF, OP, H, kt)                                             \
  do {                                                                        \
    GL16((gp) + (size_t)(H) * (128 * K_TOT) + (kt), &lds[BUF][OP][H][ldsC0]); \
    GL16((gp) + (size_t)(H) * (128 * K_TOT) + (64 * K_TOT) + (kt),            \
         &lds[BUF][OP][H][ldsC1]);                                            \
  } while (0)

  float16v acc[4][2];
#pragma unroll
  for (int m = 0; m < 4; ++m)
#pragma unroll
    for (int n = 0; n < 2; ++n)
#pragma unroll
      for (int r = 0; r < 16; ++r) acc[m][n][r] = 0.f;

  bf16x8 af[2][2];    // A frags: 2 m-blocks x {kq, kq+1}
  bf16x8 bfr[2][4];   // B frags: 2 n-blocks x 4 k-quarters (live whole tile)

#define READ_A(BUF, MB, KQ)                                                 \
  _Pragma("unroll") for (int mm = 0; mm < 2; ++mm) {                        \
    const unsigned short* ap =                                              \
        &lds[BUF][0][wr][((MB) + mm) * 2048 + rowOff32];                    \
    af[mm][0] = *(const bf16x8*)&ap[ck[KQ]];                                \
    af[mm][1] = *(const bf16x8*)&ap[ck[(KQ) + 1]];                          \
  }

#define READ_B(BUF, KQ)                                                     \
  _Pragma("unroll") for (int nn = 0; nn < 2; ++nn) {                        \
    const unsigned short* bp =                                              \
        &lds[BUF][1][wcH][(wcL * 64 + nn * 32) * 64 + rowOff32];            \
    bfr[nn][KQ] = *(const bf16x8*)&bp[ck[KQ]];                              \
    bfr[nn][(KQ) + 1] = *(const bf16x8*)&bp[ck[(KQ) + 1]];                  \
  }

#define MFMA8(MB, KQ)                                                       \
  do {                                                                      \
    __builtin_amdgcn_s_setprio(1);                                          \
    _Pragma("unroll") for (int mm = 0; mm < 2; ++mm)                        \
        _Pragma("unroll") for (int nn = 0; nn < 2; ++nn) {                  \
      acc[(MB) + mm][nn] = __builtin_amdgcn_mfma_f32_32x32x16_bf16(         \
          af[mm][0], bfr[nn][KQ], acc[(MB) + mm][nn], 0, 0, 0);             \
      acc[(MB) + mm][nn] = __builtin_amdgcn_mfma_f32_32x32x16_bf16(         \
          af[mm][1], bfr[nn][(KQ) + 1], acc[(MB) + mm][nn], 0, 0, 0);       \
    }                                                                       \
    __builtin_amdgcn_s_setprio(0);                                          \
  } while (0)

  // Cadence (race-free): A(t+1) staged P0/P1 into idle buf (its A last read
  // at (t-1).P3, barrier between); B(t+2) staged P2/P3 into cur buf (B last
  // read at t.P1, barrier between). vmcnt(4) once per tile at P3.
#define TILE(BUF, TT, DOSA, DOSB, VM)                                      \
  do {                                                                     \
    READ_A(BUF, 0, 0); READ_B(BUF, 0);                                     \
    if (DOSA) STAGE(pa, 1 - (BUF), 0, 0, ((TT) + 1) * 64);                 \
    BARRIER(); MFMA8(0, 0);                                                \
    READ_A(BUF, 0, 2); READ_B(BUF, 2);                                     \
    if (DOSA) STAGE(pa, 1 - (BUF), 0, 1, ((TT) + 1) * 64);                 \
    BARRIER(); MFMA8(0, 2);                                                \
    READ_A(BUF, 2, 0);                                                     \
    if (DOSB) STAGE(pb, BUF, 1, 0, ((TT) + 2) * 64);                       \
    BARRIER(); MFMA8(2, 0);                                                \
    READ_A(BUF, 2, 2);                                                     \
    if (DOSB) STAGE(pb, BUF, 1, 1, ((TT) + 2) * 64);                       \
    VM();                                                                  \
    BARRIER(); MFMA8(2, 2);                                                \
  } while (0)

  // prologue: tile0 {A0,A1,B0,B1} then tile1 {B0,B1}; retire tile0's 8
  STAGE(pa, 0, 0, 0, 0);
  STAGE(pa, 0, 0, 1, 0);
  STAGE(pb, 0, 1, 0, 0);
  STAGE(pb, 0, 1, 1, 0);
  STAGE(pb, 1, 1, 0, 64);
  STAGE(pb, 1, 1, 1, 64);
  VMC4();
  BARRIER();

  for (int t = 0; t < 62; t += 2) {
    TILE(0, t, 1, 1, VMC4);
    TILE(1, t + 1, 1, 1, VMC4);
  }
  TILE(0, 62, 1, 0, VMC0);   // stages A(63); B(64) skipped; drain all
  TILE(1, 63, 0, 0, VMNONE); // nothing staged, nothing waited

  // epilogue: C/D 32x32: col = lane&31, row = (r&3) + 8*(r>>2) + 4*(lane>>5)
  const int r0b = brow + wr * 128 + (kh << 2);
  const int c0b = bcol + wc * 64 + r5;
#pragma unroll
  for (int nn = 0; nn < 2; ++nn) {
    const int col = c0b + nn * 32;
    const float bv = bias[col];
#pragma unroll
    for (int mb = 0; mb < 4; ++mb) {
      const int rowb = r0b + mb * 32;
#pragma unroll
      for (int r = 0; r < 16; ++r) {
        const int row = rowb + (r & 3) + ((r >> 2) << 3);
        C[(size_t)row * N_TOT + col] = acc[mb][nn][r] + bv;
      }
    }
  }
}

extern "C" void kernel_launch(void* const* d_in, const int* in_sizes, int n_in,
                              void* d_out, int out_size, void* d_ws, size_t ws_size,
                              hipStream_t stream) {
  const float* x = (const float*)d_in[0];    // [2,2048,4096]
  const float* Wb = (const float*)d_in[1];   // [4096,4096]
  const float* bb = (const float*)d_in[2];   // [4096]
  const float* U = (const float*)d_in[3];    // [64,64,64]
  const float* V = (const float*)d_in[4];    // [64,64,64]
  const float* S = (const float*)d_in[5];    // [1]
  float* out = (float*)d_out;

  unsigned short* Weff = (unsigned short*)d_ws;                     // 32 MiB
  unsigned short* Xb =
      (unsigned short*)((char*)d_ws + (size_t)N_TOT * K_TOT * 2);   // 32 MiB
  // Ut/Vt scratch in d_out's head (1 MiB each) — overwritten by the GEMM later
  float* Ut = (float*)d_out;
  float* Vt = Ut + 262144;

  trans_uv<<<2048, 256, 0, stream>>>(U, V, Ut, Vt);
  prep_all<<<4096, 256, 0, stream>>>(Wb, Ut, Vt, S, x, Weff, Xb);

  gemm256<<<256, 512, 0, stream>>>(Xb, Weff, bb, out);
}

// Round 5
// 162.084 us; speedup vs baseline: 1.0061x; 1.0061x over previous
//
#include <hip/hip_runtime.h>

// y = x @ W_base^T + b + S * adapter(x);  adapter folds into the weight:
//   W_eff[o*64+e][i*64+d] = W_base[..] + S * U[d,i,o] * V[o,d,e]
// => one bf16 GEMM  C[4096][4096] = Xb @ W_eff^T + bias
// GEMM: 256x256 tile, BK=64, 8 waves, mfma_f32_32x32x16_bf16, 4-phase/tile
// counted-vmcnt schedule, LDS [buf][op][half][128][64],
// swizzle: phys_chunk = c ^ (row&7) ^ (((row>>3)&3)<<1)  (conflict-free under
// both consecutive-8 and stride-8 lane service groupings).

typedef __attribute__((ext_vector_type(4)))  float  float4v;
typedef __attribute__((ext_vector_type(16))) float  float16v;
typedef __attribute__((ext_vector_type(8)))  __bf16 bf16x8;
typedef __attribute__((ext_vector_type(4)))  short  short4v;

#define K_TOT 4096
#define M_TOT 4096
#define N_TOT 4096

__device__ __forceinline__ unsigned short f2bf(float f) {
  unsigned int u = __float_as_uint(f);
  u += 0x7FFFu + ((u >> 16) & 1u);
  return (unsigned short)(u >> 16);
}

// ------------- tiny transposes: Ut[i][o][d]=U[d][i][o], Vt[o][e][d]=V[o][d][e]
__global__ void trans_uv(const float* __restrict__ U, const float* __restrict__ V,
                         float* __restrict__ Ut, float* __restrict__ Vt) {
  int idx = blockIdx.x * 256 + threadIdx.x;
  if (idx < 262144) {
    int d = idx & 63, o = (idx >> 6) & 63, i = idx >> 12;
    Ut[idx] = U[(d * 64 + i) * 64 + o];
  } else {
    int j = idx - 262144;
    int d = j & 63, e = (j >> 6) & 63, o = j >> 12;
    Vt[j] = V[(o * 64 + d) * 64 + e];
  }
}

// ------------- fused prep: W_eff = bf16(W + S*Ut*Vt);  Xb = bf16(X) ---------
__global__ void prep_all(const float* __restrict__ W, const float* __restrict__ Ut,
                         const float* __restrict__ Vt, const float* __restrict__ Sp,
                         const float* __restrict__ X,
                         unsigned short* __restrict__ Weff,
                         unsigned short* __restrict__ Xb) {
  const float s = Sp[0];
  const int wq = (N_TOT * K_TOT) / 4;           // 4M quads for W
  const int total4 = wq + (M_TOT * K_TOT) / 4;  // + 4M quads for X
  for (int idx = blockIdx.x * 256 + threadIdx.x; idx < total4;
       idx += gridDim.x * 256) {
    if (idx < wq) {
      const int base = idx << 2;
      const int of = base >> 12, if0 = base & 4095;
      const int o = of >> 6, e = of & 63, i = if0 >> 6, d0 = if0 & 63;
      const float4v wv = *(const float4v*)(W + (size_t)base);
      const float4v u4 = *(const float4v*)(Ut + (i * 64 + o) * 64 + d0);
      const float4v v4 = *(const float4v*)(Vt + (o * 64 + e) * 64 + d0);
      short4v pk;
#pragma unroll
      for (int j = 0; j < 4; ++j) pk[j] = (short)f2bf(wv[j] + s * u4[j] * v4[j]);
      *(short4v*)(Weff + (size_t)base) = pk;
    } else {
      const int base = (idx - wq) << 2;
      const float4v v = *(const float4v*)(X + (size_t)base);
      short4v pk;
#pragma unroll
      for (int j = 0; j < 4; ++j) pk[j] = (short)f2bf(v[j]);
      *(short4v*)(Xb + (size_t)base) = pk;
    }
  }
}

// ---------------- 256x256 GEMM, 32x32x16 MFMA -------------------------------
#define GL16(g, l)                                                    \
  __builtin_amdgcn_global_load_lds(                                   \
      (__attribute__((address_space(1))) void*)(g),                   \
      (__attribute__((address_space(3))) void*)(l), 16, 0, 0)

#define BARRIER() asm volatile("s_barrier" ::: "memory")
#define VMC4() asm volatile("s_waitcnt vmcnt(4)" ::: "memory")
#define VMC0() asm volatile("s_waitcnt vmcnt(0)" ::: "memory")
#define VMNONE()

__global__ __launch_bounds__(512, 2) void gemm256(
    const unsigned short* __restrict__ A,    // [4096][4096] bf16 (X)
    const unsigned short* __restrict__ Bm,   // [4096][4096] bf16 (W_eff)
    const float* __restrict__ bias,
    float* __restrict__ C) {
  // [buf][op A=0/B=1][row-half][128 rows][64 cols bf16] = 128 KiB
  __shared__ unsigned short lds[2][2][2][8192];

  const int tid = threadIdx.x;
  const int w = tid >> 6;
  const int l = tid & 63;
  const int r5 = l & 31;        // MFMA row/col within 32
  const int kh = l >> 5;        // k-half selector
  const int rowOff32 = r5 * 64; // ushort offset of lane's row

  // XCD-aware bijective swizzle (256 blocks, 256 % 8 == 0)
  int b = blockIdx.x;
  b = (b & 7) * 32 + (b >> 3);
  const int brow = (b >> 4) * 256;
  const int bcol = (b & 15) * 256;

  const int wr = w >> 2;        // 0..1 -> 128-row half of A-tile
  const int wc = w & 3;         // 0..3 -> 64-row slice of B-tile
  const int wcH = wc >> 1, wcL = wc & 1;

  // read-side swizzle key: pure function of row within the half
  // key(row) = (row&7) ^ (((row>>3)&3)<<1); here row ≡ r5 (mod 32) and the
  // higher row bits contribute 0 (all block offsets are multiples of 32).
  const int key = (r5 & 7) ^ (((r5 >> 3) & 3) << 1);
  int ck[4];
#pragma unroll
  for (int q = 0; q < 4; ++q) ck[q] = (((q * 2 + kh) ^ key) << 3);

  // stage-side inverse: lane l covers phys chunk (w*64 + l); row = w*8 + (l>>3)
  // logical chunk cL = (l&7) ^ key(row) = (l&7) ^ (l>>3) ^ ((w&3)<<1)
  const int rowL = l >> 3;
  const int cL = (l & 7) ^ rowL ^ ((w & 3) << 1);
  const unsigned short* pa = A + (size_t)(brow + w * 8 + rowL) * K_TOT + cL * 8;
  const unsigned short* pb = Bm + (size_t)(bcol + w * 8 + rowL) * K_TOT + cL * 8;
  const int ldsC0 = (w * 64) * 8;        // wave chunk base, rows 0-63 of half
  const int ldsC1 = (512 + w * 64) * 8;  // rows 64-127

#define STAGE(gp, BUF, OP, H, kt)                                             \
  do {                                                                        \
    GL16((gp) + (size_t)(H) * (128 * K_TOT) + (kt), &lds[BUF][OP][H][ldsC0]); \
    GL16((gp) + (size_t)(H) * (128 * K_TOT) + (64 * K_TOT) + (kt),            \
         &lds[BUF][OP][H][ldsC1]);                                            \
  } while (0)

  float16v acc[4][2];
#pragma unroll
  for (int m = 0; m < 4; ++m)
#pragma unroll
    for (int n = 0; n < 2; ++n)
#pragma unroll
      for (int r = 0; r < 16; ++r) acc[m][n][r] = 0.f;

  bf16x8 af[2][2];    // A frags: 2 m-blocks x {kq, kq+1}
  bf16x8 bfr[2][4];   // B frags: 2 n-blocks x 4 k-quarters (live whole tile)

#define READ_A(BUF, MB, KQ)                                                 \
  _Pragma("unroll") for (int mm = 0; mm < 2; ++mm) {                        \
    const unsigned short* ap =                                              \
        &lds[BUF][0][wr][((MB) + mm) * 2048 + rowOff32];                    \
    af[mm][0] = *(const bf16x8*)&ap[ck[KQ]];                                \
    af[mm][1] = *(const bf16x8*)&ap[ck[(KQ) + 1]];                          \
  }

#define READ_B(BUF, KQ)                                                     \
  _Pragma("unroll") for (int nn = 0; nn < 2; ++nn) {                        \
    const unsigned short* bp =                                              \
        &lds[BUF][1][wcH][(wcL * 64 + nn * 32) * 64 + rowOff32];            \
    bfr[nn][KQ] = *(const bf16x8*)&bp[ck[KQ]];                              \
    bfr[nn][(KQ) + 1] = *(const bf16x8*)&bp[ck[(KQ) + 1]];                  \
  }

#define MFMA8(MB, KQ)                                                       \
  do {                                                                      \
    __builtin_amdgcn_s_setprio(1);                                          \
    _Pragma("unroll") for (int mm = 0; mm < 2; ++mm)                        \
        _Pragma("unroll") for (int nn = 0; nn < 2; ++nn) {                  \
      acc[(MB) + mm][nn] = __builtin_amdgcn_mfma_f32_32x32x16_bf16(         \
          af[mm][0], bfr[nn][KQ], acc[(MB) + mm][nn], 0, 0, 0);             \
      acc[(MB) + mm][nn] = __builtin_amdgcn_mfma_f32_32x32x16_bf16(         \
          af[mm][1], bfr[nn][(KQ) + 1], acc[(MB) + mm][nn], 0, 0, 0);       \
    }                                                                       \
    __builtin_amdgcn_s_setprio(0);                                          \
  } while (0)

  // Cadence (race-free): A(t+1) staged P0/P1 into idle buf (its A last read
  // at (t-1).P3, barrier between); B(t+2) staged P2/P3 into cur buf (B last
  // read at t.P1, barrier between). vmcnt(4) once per tile at P3.
#define TILE(BUF, TT, DOSA, DOSB, VM)                                      \
  do {                                                                     \
    READ_A(BUF, 0, 0); READ_B(BUF, 0);                                     \
    if (DOSA) STAGE(pa, 1 - (BUF), 0, 0, ((TT) + 1) * 64);                 \
    BARRIER(); MFMA8(0, 0);                                                \
    READ_A(BUF, 0, 2); READ_B(BUF, 2);                                     \
    if (DOSA) STAGE(pa, 1 - (BUF), 0, 1, ((TT) + 1) * 64);                 \
    BARRIER(); MFMA8(0, 2);                                                \
    READ_A(BUF, 2, 0);                                                     \
    if (DOSB) STAGE(pb, BUF, 1, 0, ((TT) + 2) * 64);                       \
    BARRIER(); MFMA8(2, 0);                                                \
    READ_A(BUF, 2, 2);                                                     \
    if (DOSB) STAGE(pb, BUF, 1, 1, ((TT) + 2) * 64);                       \
    VM();                                                                  \
    BARRIER(); MFMA8(2, 2);                                                \
  } while (0)

  // prologue: tile0 {A0,A1,B0,B1} then tile1 {B0,B1}; retire tile0's 8
  STAGE(pa, 0, 0, 0, 0);
  STAGE(pa, 0, 0, 1, 0);
  STAGE(pb, 0, 1, 0, 0);
  STAGE(pb, 0, 1, 1, 0);
  STAGE(pb, 1, 1, 0, 64);
  STAGE(pb, 1, 1, 1, 64);
  VMC4();
  BARRIER();

  for (int t = 0; t < 62; t += 2) {
    TILE(0, t, 1, 1, VMC4);
    TILE(1, t + 1, 1, 1, VMC4);
  }
  TILE(0, 62, 1, 0, VMC0);   // stages A(63); B(64) skipped; drain all
  TILE(1, 63, 0, 0, VMNONE); // nothing staged, nothing waited

  // epilogue: C/D 32x32: col = lane&31, row = (r&3) + 8*(r>>2) + 4*(lane>>5)
  const int r0b = brow + wr * 128 + (kh << 2);
  const int c0b = bcol + wc * 64 + r5;
#pragma unroll
  for (int nn = 0; nn < 2; ++nn) {
    const int col = c0b + nn * 32;
    const float bv = bias[col];
#pragma unroll
    for (int mb = 0; mb < 4; ++mb) {
      const int rowb = r0b + mb * 32;
#pragma unroll
      for (int r = 0; r < 16; ++r) {
        const int row = rowb + (r & 3) + ((r >> 2) << 3);
        C[(size_t)row * N_TOT + col] = acc[mb][nn][r] + bv;
      }
    }
  }
}

extern "C" void kernel_launch(void* const* d_in, const int* in_sizes, int n_in,
                              void* d_out, int out_size, void* d_ws, size_t ws_size,
                              hipStream_t stream) {
  const float* x = (const float*)d_in[0];    // [2,2048,4096]
  const float* Wb = (const float*)d_in[1];   // [4096,4096]
  const float* bb = (const float*)d_in[2];   // [4096]
  const float* U = (const float*)d_in[3];    // [64,64,64]
  const float* V = (const float*)d_in[4];    // [64,64,64]
  const float* S = (const float*)d_in[5];    // [1]
  float* out = (float*)d_out;

  unsigned short* Weff = (unsigned short*)d_ws;                     // 32 MiB
  unsigned short* Xb =
      (unsigned short*)((char*)d_ws + (size_t)N_TOT * K_TOT * 2);   // 32 MiB
  // Ut/Vt scratch in d_out's head (1 MiB each) — overwritten by the GEMM later
  float* Ut = (float*)d_out;
  float* Vt = Ut + 262144;

  trans_uv<<<2048, 256, 0, stream>>>(U, V, Ut, Vt);
  prep_all<<<4096, 256, 0, stream>>>(Wb, Ut, Vt, S, x, Weff, Xb);

  gemm256<<<256, 512, 0, stream>>>(Xb, Weff, bb, out);
}

// Round 6
// 151.717 us; speedup vs baseline: 1.0749x; 1.0683x over previous
//
#include <hip/hip_runtime.h>

// y = x @ W_base^T + b + S * adapter(x);  adapter folds into the weight:
//   W_eff[o*64+e][i*64+d] = W_base[..] + S * U[d,i,o] * V[o,d,e]
// => one bf16 GEMM  C[4096][4096] = Xb @ W_eff^T + bias
// GEMM: 256x256 tile, BK=64, 8 waves, mfma 16x16x32 (proven 0-conflict layout),
// m201-style schedule: 2 barriers/phase, deep stage cadence, vmcnt(6).

typedef __attribute__((ext_vector_type(4))) float  float4v;
typedef __attribute__((ext_vector_type(8))) __bf16 bf16x8;
typedef __attribute__((ext_vector_type(4))) short  short4v;

#define K_TOT 4096
#define M_TOT 4096
#define N_TOT 4096

__device__ __forceinline__ unsigned short f2bf(float f) {
  unsigned int u = __float_as_uint(f);
  u += 0x7FFFu + ((u >> 16) & 1u);
  return (unsigned short)(u >> 16);
}

// ------------- tiny transposes: Ut[i][o][d]=U[d][i][o], Vt[o][e][d]=V[o][d][e]
__global__ void trans_uv(const float* __restrict__ U, const float* __restrict__ V,
                         float* __restrict__ Ut, float* __restrict__ Vt) {
  int idx = blockIdx.x * 256 + threadIdx.x;
  if (idx < 262144) {
    int d = idx & 63, o = (idx >> 6) & 63, i = idx >> 12;
    Ut[idx] = U[(d * 64 + i) * 64 + o];
  } else {
    int j = idx - 262144;
    int d = j & 63, e = (j >> 6) & 63, o = j >> 12;
    Vt[j] = V[(o * 64 + d) * 64 + e];
  }
}

// ------------- fused prep: W_eff = bf16(W + S*Ut*Vt);  Xb = bf16(X) ---------
__global__ void prep_all(const float* __restrict__ W, const float* __restrict__ Ut,
                         const float* __restrict__ Vt, const float* __restrict__ Sp,
                         const float* __restrict__ X,
                         unsigned short* __restrict__ Weff,
                         unsigned short* __restrict__ Xb) {
  const float s = Sp[0];
  const int wq = (N_TOT * K_TOT) / 4;
  const int total4 = wq + (M_TOT * K_TOT) / 4;
  for (int idx = blockIdx.x * 256 + threadIdx.x; idx < total4;
       idx += gridDim.x * 256) {
    if (idx < wq) {
      const int base = idx << 2;
      const int of = base >> 12, if0 = base & 4095;
      const int o = of >> 6, e = of & 63, i = if0 >> 6, d0 = if0 & 63;
      const float4v wv = *(const float4v*)(W + (size_t)base);
      const float4v u4 = *(const float4v*)(Ut + (i * 64 + o) * 64 + d0);
      const float4v v4 = *(const float4v*)(Vt + (o * 64 + e) * 64 + d0);
      short4v pk;
#pragma unroll
      for (int j = 0; j < 4; ++j) pk[j] = (short)f2bf(wv[j] + s * u4[j] * v4[j]);
      *(short4v*)(Weff + (size_t)base) = pk;
    } else {
      const int base = (idx - wq) << 2;
      const float4v v = *(const float4v*)(X + (size_t)base);
      short4v pk;
#pragma unroll
      for (int j = 0; j < 4; ++j) pk[j] = (short)f2bf(v[j]);
      *(short4v*)(Xb + (size_t)base) = pk;
    }
  }
}

// ---------------- 256x256 8-phase GEMM --------------------------------------
#define GL16(g, l)                                                    \
  __builtin_amdgcn_global_load_lds(                                   \
      (__attribute__((address_space(1))) void*)(g),                   \
      (__attribute__((address_space(3))) void*)(l), 16, 0, 0)

#define BARRIER() asm volatile("s_barrier" ::: "memory")
#define VMC6() asm volatile("s_waitcnt vmcnt(6)" ::: "memory")
#define VMC0() asm volatile("s_waitcnt vmcnt(0)" ::: "memory")
#define VMNONE()

__global__ __launch_bounds__(512, 2) void gemm256(
    const unsigned short* __restrict__ A,    // [4096][4096] bf16 (X)
    const unsigned short* __restrict__ Bm,   // [4096][4096] bf16 (W_eff)
    const float* __restrict__ bias,
    float* __restrict__ C) {
  // [buf][op A=0/B=1][row-half][128 rows][64 cols bf16] = 128 KiB
  __shared__ unsigned short lds[2][2][2][8192];

  const int tid = threadIdx.x;
  const int w = tid >> 6;
  const int l = tid & 63;
  const int l15 = l & 15;
  const int hi = l >> 4;

  // XCD-aware bijective swizzle (256 blocks, 256 % 8 == 0)
  int b = blockIdx.x;
  b = (b & 7) * 32 + (b >> 3);
  const int brow = (b >> 4) * 256;
  const int bcol = (b & 15) * 256;

  const int wr = w >> 2;        // 0..1 -> 128-row half of A-tile
  const int wc = w & 3;         // 0..3 -> 64-row slice of B-tile
  const int wcH = wc >> 1, wcL = wc & 1;

  // read-side T2 swizzle (round-3 exact, measured 0 conflicts):
  // logical chunk (kk*4 + hi) ^ (row&7), row%16 == l15
  const int b2 = (l15 >> 2) & 1;
  const int cx = hi ^ (l15 & 3);
  const int rdK0 = (((b2 ^ 0) << 2) | cx) << 3;   // kk=0 chunk offset (ushorts)
  const int rdK1 = (((b2 ^ 1) << 2) | cx) << 3;   // kk=1
  const int rowOff = l15 << 6;                    // l15 * 64 ushorts

  // stage-side inverse: lane covers phys chunk (w*64 + l); row = w*8 + (l>>3)
  const int rowL = l >> 3;
  const int cL = (l & 7) ^ rowL;
  const unsigned short* pa = A + (size_t)(brow + w * 8 + rowL) * K_TOT + cL * 8;
  const unsigned short* pb = Bm + (size_t)(bcol + w * 8 + rowL) * K_TOT + cL * 8;
  const int ldsC0 = (w * 64) * 8;        // wave chunk base, rows 0-63 of half
  const int ldsC1 = (512 + w * 64) * 8;  // rows 64-127

#define STAGE(gp, BUF, OP, H, kt)                                             \
  do {                                                                        \
    GL16((gp) + (size_t)(H) * (128 * K_TOT) + (kt), &lds[BUF][OP][H][ldsC0]); \
    GL16((gp) + (size_t)(H) * (128 * K_TOT) + (64 * K_TOT) + (kt),            \
         &lds[BUF][OP][H][ldsC1]);                                            \
  } while (0)

  float4v acc[8][4];
#pragma unroll
  for (int m = 0; m < 8; ++m)
#pragma unroll
    for (int j = 0; j < 4; ++j) acc[m][j] = (float4v){0.f, 0.f, 0.f, 0.f};
  bf16x8 af[4][2];    // A frags: 4 m-rows x 2 kk (m-low then m-high)
  bf16x8 bfr[4][2];   // B frags: 4 n x 2 kk (live whole tile)

#define READ_A(BUF, MB)                                                     \
  _Pragma("unroll") for (int mm = 0; mm < 4; ++mm) {                        \
    const unsigned short* ap =                                              \
        &lds[BUF][0][wr][((MB) + mm) * 1024 + rowOff];                      \
    af[mm][0] = *(const bf16x8*)&ap[rdK0];                                  \
    af[mm][1] = *(const bf16x8*)&ap[rdK1];                                  \
  }

#define READ_B(BUF, NH)                                                     \
  _Pragma("unroll") for (int jj = 0; jj < 2; ++jj) {                        \
    const unsigned short* bp =                                              \
        &lds[BUF][1][wcH]                                                   \
            [((wcL)*64 + (NH)*32 + jj * 16) * 64 + rowOff];                 \
    bfr[(NH)*2 + jj][0] = *(const bf16x8*)&bp[rdK0];                        \
    bfr[(NH)*2 + jj][1] = *(const bf16x8*)&bp[rdK1];                        \
  }

#define MFMA16(MB, NB)                                                      \
  do {                                                                      \
    __builtin_amdgcn_s_setprio(1);                                          \
    _Pragma("unroll") for (int mm = 0; mm < 4; ++mm)                        \
        _Pragma("unroll") for (int nn = 0; nn < 2; ++nn) {                  \
      acc[(MB) + mm][(NB) + nn] = __builtin_amdgcn_mfma_f32_16x16x32_bf16(  \
          af[mm][0], bfr[(NB) + nn][0], acc[(MB) + mm][(NB) + nn], 0, 0, 0);\
      acc[(MB) + mm][(NB) + nn] = __builtin_amdgcn_mfma_f32_16x16x32_bf16(  \
          af[mm][1], bfr[(NB) + nn][1], acc[(MB) + mm][(NB) + nn], 0, 0, 0);\
    }                                                                       \
    __builtin_amdgcn_s_setprio(0);                                          \
  } while (0)

  // m201-style halfiter (tile TT in buf BUF), 4 phases x {reads; stage;
  // barrier; MFMA; [vm]; barrier}. Stage cadence (earliest-legal):
  //   P0: Ah1(TT+1)->buf^1   (A(TT-1) last read at prev P2, 2 barriers ago)
  //   P2: Bh0(TT+2)->buf     (B(TT) last read P1, post-barrier between)
  //   P3: Bh1(TT+2), Ah0(TT+2)->buf  (A(TT) last read P2)
  // vmcnt(6) at P3 retires through Ah1(TT+1): tile TT+1 fully landed before
  // the P3 post-barrier; 6 newest (P2+P3 stages) stay in flight.
#define HALFITER(BUF, TT, DA1, DB, DA2, VM)                                 \
  do {                                                                      \
    READ_A(BUF, 0); READ_B(BUF, 0);                                         \
    if (DA1) STAGE(pa, 1 - (BUF), 0, 1, ((TT) + 1) * 64);                   \
    BARRIER(); MFMA16(0, 0); BARRIER();                                     \
    READ_B(BUF, 1);                                                         \
    BARRIER(); MFMA16(0, 2); BARRIER();                                     \
    READ_A(BUF, 4);                                                         \
    if (DB) STAGE(pb, BUF, 1, 0, ((TT) + 2) * 64);                          \
    BARRIER(); MFMA16(4, 0); BARRIER();                                     \
    if (DB) STAGE(pb, BUF, 1, 1, ((TT) + 2) * 64);                          \
    if (DA2) STAGE(pa, BUF, 0, 0, ((TT) + 2) * 64);                         \
    BARRIER(); MFMA16(4, 2); VM(); BARRIER();                               \
  } while (0)

  // prologue: tile0 complete, tile1 {Bh0,Bh1,Ah0}; Ah1(1) staged at H0.P0.
  STAGE(pa, 0, 0, 0, 0);     // Ah0(0)
  STAGE(pa, 0, 0, 1, 0);     // Ah1(0)
  STAGE(pb, 0, 1, 0, 0);     // Bh0(0)
  STAGE(pb, 0, 1, 1, 0);     // Bh1(0)
  STAGE(pb, 1, 1, 0, 64);    // Bh0(1)
  STAGE(pb, 1, 1, 1, 64);    // Bh1(1)
  STAGE(pa, 1, 0, 0, 64);    // Ah0(1)
  VMC6();                    // retire tile0's 8 loads; 6 stay in flight
  BARRIER();

  for (int t = 0; t < 62; t += 2) {
    HALFITER(0, t, 1, 1, 1, VMC6);
    HALFITER(1, t + 1, 1, 1, 1, VMC6);
  }
  HALFITER(0, 62, 1, 0, 0, VMC0);    // stages Ah1(63) only; drain all
  HALFITER(1, 63, 0, 0, 0, VMNONE);  // nothing staged, nothing waited

  // epilogue: C/D layout col = lane&15, row = (lane>>4)*4 + v
  const int r0 = brow + wr * 128 + (l >> 4) * 4;
  const int c0 = bcol + wc * 64;
#pragma unroll
  for (int j = 0; j < 4; ++j) {
    const int col = c0 + j * 16 + l15;
    const float bv = bias[col];
#pragma unroll
    for (int m = 0; m < 8; ++m) {
      const int row = r0 + m * 16;
#pragma unroll
      for (int v = 0; v < 4; ++v)
        C[(size_t)(row + v) * N_TOT + col] = acc[m][j][v] + bv;
    }
  }
}

extern "C" void kernel_launch(void* const* d_in, const int* in_sizes, int n_in,
                              void* d_out, int out_size, void* d_ws, size_t ws_size,
                              hipStream_t stream) {
  const float* x = (const float*)d_in[0];    // [2,2048,4096]
  const float* Wb = (const float*)d_in[1];   // [4096,4096]
  const float* bb = (const float*)d_in[2];   // [4096]
  const float* U = (const float*)d_in[3];    // [64,64,64]
  const float* V = (const float*)d_in[4];    // [64,64,64]
  const float* S = (const float*)d_in[5];    // [1]
  float* out = (float*)d_out;

  unsigned short* Weff = (unsigned short*)d_ws;                     // 32 MiB
  unsigned short* Xb =
      (unsigned short*)((char*)d_ws + (size_t)N_TOT * K_TOT * 2);   // 32 MiB
  // Ut/Vt scratch in d_out's head (1 MiB each) — overwritten by the GEMM later
  float* Ut = (float*)d_out;
  float* Vt = Ut + 262144;

  trans_uv<<<2048, 256, 0, stream>>>(U, V, Ut, Vt);
  prep_all<<<4096, 256, 0, stream>>>(Wb, Ut, Vt, S, x, Weff, Xb);

  gemm256<<<256, 512, 0, stream>>>(Xb, Weff, bb, out);
}

// Round 7
// 145.658 us; speedup vs baseline: 1.1196x; 1.0416x over previous
//
#include <hip/hip_runtime.h>

// y = x @ W_base^T + b + S * adapter(x);  adapter folds into the weight:
//   W_eff[o*64+e][i*64+d] = W_base[..] + S * U[d,i,o] * V[o,d,e]
// => one bf16 GEMM  C[4096][4096] = Xb @ W_eff^T + bias
// GEMM: round-3 exact (best measured: 109.5us, 0 bank conflicts, MfmaUtil 55.6%):
//   256x256 tile, BK=64, 8 waves, mfma 16x16x32, 4 phases/tile (1 barrier each),
//   stage cadence A(t+1)@P0/P1 -> idle buf, B(t+2)@P2/P3 -> cur buf, vmcnt(4)@P3.
// Prep: round-6 fused path (trans_uv + prep_all).

typedef __attribute__((ext_vector_type(4))) float  float4v;
typedef __attribute__((ext_vector_type(8))) __bf16 bf16x8;
typedef __attribute__((ext_vector_type(4))) short  short4v;

#define K_TOT 4096
#define M_TOT 4096
#define N_TOT 4096

__device__ __forceinline__ unsigned short f2bf(float f) {
  unsigned int u = __float_as_uint(f);
  u += 0x7FFFu + ((u >> 16) & 1u);
  return (unsigned short)(u >> 16);
}

// ------------- tiny transposes: Ut[i][o][d]=U[d][i][o], Vt[o][e][d]=V[o][d][e]
__global__ void trans_uv(const float* __restrict__ U, const float* __restrict__ V,
                         float* __restrict__ Ut, float* __restrict__ Vt) {
  int idx = blockIdx.x * 256 + threadIdx.x;
  if (idx < 262144) {
    int d = idx & 63, o = (idx >> 6) & 63, i = idx >> 12;
    Ut[idx] = U[(d * 64 + i) * 64 + o];
  } else {
    int j = idx - 262144;
    int d = j & 63, e = (j >> 6) & 63, o = j >> 12;
    Vt[j] = V[(o * 64 + d) * 64 + e];
  }
}

// ------------- fused prep: W_eff = bf16(W + S*Ut*Vt);  Xb = bf16(X) ---------
__global__ void prep_all(const float* __restrict__ W, const float* __restrict__ Ut,
                         const float* __restrict__ Vt, const float* __restrict__ Sp,
                         const float* __restrict__ X,
                         unsigned short* __restrict__ Weff,
                         unsigned short* __restrict__ Xb) {
  const float s = Sp[0];
  const int wq = (N_TOT * K_TOT) / 4;
  const int total4 = wq + (M_TOT * K_TOT) / 4;
  for (int idx = blockIdx.x * 256 + threadIdx.x; idx < total4;
       idx += gridDim.x * 256) {
    if (idx < wq) {
      const int base = idx << 2;
      const int of = base >> 12, if0 = base & 4095;
      const int o = of >> 6, e = of & 63, i = if0 >> 6, d0 = if0 & 63;
      const float4v wv = *(const float4v*)(W + (size_t)base);
      const float4v u4 = *(const float4v*)(Ut + (i * 64 + o) * 64 + d0);
      const float4v v4 = *(const float4v*)(Vt + (o * 64 + e) * 64 + d0);
      short4v pk;
#pragma unroll
      for (int j = 0; j < 4; ++j) pk[j] = (short)f2bf(wv[j] + s * u4[j] * v4[j]);
      *(short4v*)(Weff + (size_t)base) = pk;
    } else {
      const int base = (idx - wq) << 2;
      const float4v v = *(const float4v*)(X + (size_t)base);
      short4v pk;
#pragma unroll
      for (int j = 0; j < 4; ++j) pk[j] = (short)f2bf(v[j]);
      *(short4v*)(Xb + (size_t)base) = pk;
    }
  }
}

// ---------------- 256x256 8-phase GEMM (round-3 exact) ----------------------
#define GL16(g, l)                                                    \
  __builtin_amdgcn_global_load_lds(                                   \
      (__attribute__((address_space(1))) void*)(g),                   \
      (__attribute__((address_space(3))) void*)(l), 16, 0, 0)

#define BARRIER() asm volatile("s_barrier" ::: "memory")
#define VMC4() asm volatile("s_waitcnt vmcnt(4)" ::: "memory")
#define VMC0() asm volatile("s_waitcnt vmcnt(0)" ::: "memory")
#define VMNONE()

__global__ __launch_bounds__(512, 2) void gemm256(
    const unsigned short* __restrict__ A,    // [4096][4096] bf16 (X)
    const unsigned short* __restrict__ Bm,   // [4096][4096] bf16 (W_eff)
    const float* __restrict__ bias,
    float* __restrict__ C) {
  // [buf][op A=0/B=1][row-half][128 rows][64 cols bf16] = 128 KiB
  __shared__ unsigned short lds[2][2][2][8192];

  const int tid = threadIdx.x;
  const int w = tid >> 6;
  const int l = tid & 63;
  const int l15 = l & 15;
  const int hi = l >> 4;

  // XCD-aware bijective swizzle (256 blocks, 256 % 8 == 0)
  int b = blockIdx.x;
  b = (b & 7) * 32 + (b >> 3);
  const int brow = (b >> 4) * 256;
  const int bcol = (b & 15) * 256;

  const int wr = w >> 2;        // 0..1 -> 128-row half of A-tile
  const int wc = w & 3;         // 0..3 -> 64-row slice of B-tile
  const int wcH = wc >> 1, wcL = wc & 1;

  // read-side T2 swizzle: logical chunk (kk*4 + hi) ^ (row&7), row%16 == l15
  const int b2 = (l15 >> 2) & 1;
  const int cx = hi ^ (l15 & 3);
  const int rdK0 = (((b2 ^ 0) << 2) | cx) << 3;   // kk=0 chunk offset (ushorts)
  const int rdK1 = (((b2 ^ 1) << 2) | cx) << 3;   // kk=1
  const int rowOff = l15 << 6;                    // l15 * 64 ushorts

  // stage-side inverse: lane covers phys chunk (w*64 + l); row = w*8 + (l>>3)
  const int rowL = l >> 3;
  const int cL = (l & 7) ^ rowL;
  const unsigned short* pa = A + (size_t)(brow + w * 8 + rowL) * K_TOT + cL * 8;
  const unsigned short* pb = Bm + (size_t)(bcol + w * 8 + rowL) * K_TOT + cL * 8;
  const int ldsC0 = (w * 64) * 8;        // wave chunk base, rows 0-63 of half
  const int ldsC1 = (512 + w * 64) * 8;  // rows 64-127

#define STAGE(gp, BUF, OP, H, kt)                                             \
  do {                                                                        \
    GL16((gp) + (size_t)(H) * (128 * K_TOT) + (kt), &lds[BUF][OP][H][ldsC0]); \
    GL16((gp) + (size_t)(H) * (128 * K_TOT) + (64 * K_TOT) + (kt),            \
         &lds[BUF][OP][H][ldsC1]);                                            \
  } while (0)

  float4v acc[8][4];
#pragma unroll
  for (int m = 0; m < 8; ++m)
#pragma unroll
    for (int j = 0; j < 4; ++j) acc[m][j] = (float4v){0.f, 0.f, 0.f, 0.f};
  bf16x8 af[4][2];    // A frags: 4 m-rows x 2 kk
  bf16x8 bfr[4][2];   // B frags: 4 n x 2 kk (live whole tile)

#define READ_A(BUF, MB)                                                     \
  _Pragma("unroll") for (int mm = 0; mm < 4; ++mm) {                        \
    const unsigned short* ap =                                              \
        &lds[BUF][0][wr][((MB) + mm) * 1024 + rowOff];                      \
    af[mm][0] = *(const bf16x8*)&ap[rdK0];                                  \
    af[mm][1] = *(const bf16x8*)&ap[rdK1];                                  \
  }

#define READ_B(BUF, NH)                                                     \
  _Pragma("unroll") for (int jj = 0; jj < 2; ++jj) {                        \
    const unsigned short* bp =                                              \
        &lds[BUF][1][wcH]                                                   \
            [((wcL)*64 + (NH)*32 + jj * 16) * 64 + rowOff];                 \
    bfr[(NH)*2 + jj][0] = *(const bf16x8*)&bp[rdK0];                        \
    bfr[(NH)*2 + jj][1] = *(const bf16x8*)&bp[rdK1];                        \
  }

#define MFMA16(MB, NB)                                                      \
  do {                                                                      \
    __builtin_amdgcn_s_setprio(1);                                          \
    _Pragma("unroll") for (int mm = 0; mm < 4; ++mm)                        \
        _Pragma("unroll") for (int nn = 0; nn < 2; ++nn) {                  \
      acc[(MB) + mm][(NB) + nn] = __builtin_amdgcn_mfma_f32_16x16x32_bf16(  \
          af[mm][0], bfr[(NB) + nn][0], acc[(MB) + mm][(NB) + nn], 0, 0, 0);\
      acc[(MB) + mm][(NB) + nn] = __builtin_amdgcn_mfma_f32_16x16x32_bf16(  \
          af[mm][1], bfr[(NB) + nn][1], acc[(MB) + mm][(NB) + nn], 0, 0, 0);\
    }                                                                       \
    __builtin_amdgcn_s_setprio(0);                                          \
  } while (0)

  // Cadence (race-free): A(t+1) staged P0/P1 into idle buf (its A last read
  // at (t-1).P3, barrier between); B(t+2) staged P2/P3 into cur buf (B last
  // read at t.P1, barrier between). vmcnt(4) once per tile at P3.
#define TILE(BUF, TT, DOSA, DOSB, VM)                                      \
  do {                                                                     \
    READ_A(BUF, 0); READ_B(BUF, 0);                                        \
    if (DOSA) STAGE(pa, 1 - (BUF), 0, 0, ((TT) + 1) * 64);                 \
    BARRIER(); MFMA16(0, 0);                                               \
    READ_B(BUF, 1);                                                        \
    if (DOSA) STAGE(pa, 1 - (BUF), 0, 1, ((TT) + 1) * 64);                 \
    BARRIER(); MFMA16(0, 2);                                               \
    READ_A(BUF, 4);                                                        \
    if (DOSB) STAGE(pb, BUF, 1, 0, ((TT) + 2) * 64);                       \
    BARRIER(); MFMA16(4, 0);                                               \
    if (DOSB) STAGE(pb, BUF, 1, 1, ((TT) + 2) * 64);                       \
    VM();                                                                  \
    BARRIER(); MFMA16(4, 2);                                               \
  } while (0)

  // prologue: tile0 {A0,A1,B0,B1} then tile1 {B0,B1}; retire tile0's 8
  STAGE(pa, 0, 0, 0, 0);
  STAGE(pa, 0, 0, 1, 0);
  STAGE(pb, 0, 1, 0, 0);
  STAGE(pb, 0, 1, 1, 0);
  STAGE(pb, 1, 1, 0, 64);
  STAGE(pb, 1, 1, 1, 64);
  VMC4();
  BARRIER();

  for (int t = 0; t < 62; t += 2) {
    TILE(0, t, 1, 1, VMC4);
    TILE(1, t + 1, 1, 1, VMC4);
  }
  TILE(0, 62, 1, 0, VMC0);   // stages A(63); B(64) skipped; drain all
  TILE(1, 63, 0, 0, VMNONE); // nothing staged, nothing waited

  // epilogue: C/D layout col = lane&15, row = (lane>>4)*4 + v
  const int r0 = brow + wr * 128 + (l >> 4) * 4;
  const int c0 = bcol + wc * 64;
#pragma unroll
  for (int j = 0; j < 4; ++j) {
    const int col = c0 + j * 16 + l15;
    const float bv = bias[col];
#pragma unroll
    for (int m = 0; m < 8; ++m) {
      const int row = r0 + m * 16;
#pragma unroll
      for (int v = 0; v < 4; ++v)
        C[(size_t)(row + v) * N_TOT + col] = acc[m][j][v] + bv;
    }
  }
}

extern "C" void kernel_launch(void* const* d_in, const int* in_sizes, int n_in,
                              void* d_out, int out_size, void* d_ws, size_t ws_size,
                              hipStream_t stream) {
  const float* x = (const float*)d_in[0];    // [2,2048,4096]
  const float* Wb = (const float*)d_in[1];   // [4096,4096]
  const float* bb = (const float*)d_in[2];   // [4096]
  const float* U = (const float*)d_in[3];    // [64,64,64]
  const float* V = (const float*)d_in[4];    // [64,64,64]
  const float* S = (const float*)d_in[5];    // [1]
  float* out = (float*)d_out;

  unsigned short* Weff = (unsigned short*)d_ws;                     // 32 MiB
  unsigned short* Xb =
      (unsigned short*)((char*)d_ws + (size_t)N_TOT * K_TOT * 2);   // 32 MiB
  // Ut/Vt scratch in d_out's head (1 MiB each) — overwritten by the GEMM later
  float* Ut = (float*)d_out;
  float* Vt = Ut + 262144;

  trans_uv<<<2048, 256, 0, stream>>>(U, V, Ut, Vt);
  prep_all<<<4096, 256, 0, stream>>>(Wb, Ut, Vt, S, x, Weff, Xb);

  gemm256<<<256, 512, 0, stream>>>(Xb, Weff, bb, out);
}